// Round 1
// 325.017 us; speedup vs baseline: 1.0619x; 1.0619x over previous
//
#include <hip/hip_runtime.h>

// Embedding gather, inverted: stream W once (coalesced), scatter to out.
//
//   x: [16384] int32 token ids
//   W: [DIMS=1024, TOKENS=50257] float32 row-major (token vec = COLUMN of W)
//   out: [16384, 1024] float32
//
// R0 lesson: per-token column gather fetches 64B/sector per 4B load with zero
// reuse -> 1.05 GB HBM fetch. Fix: counting-sort tokens into windows of
// consecutive ids; one block per (window, dim-chunk) stages the W tile via
// coalesced reads into LDS and writes each resident token's dims contiguously.
//
// R1 changes:
//  - Fuse zero+hist+scan+scatter (4 launches) into ONE single-workgroup kernel:
//    x staged in LDS (64 KB), LDS-atomic histogram over 393 bins, LDS
//    Hillis-Steele scan, LDS-atomic scatter. Kills 3 launches + global hist
//    round-trips.
//  - Window 64 -> 128 ids, dim chunk 64 -> 128 (tile 128x128, 512 threads,
//    LDS pad 129 -> bank (d+c)&31, conflict-free both phases). Read granule
//    256B -> 512B per W row (50257*4 % 64 = 4, so misaligned sector-split
//    overhead halves: ~257 MB -> ~232 MB fetch); write granule per out row
//    256B x16 blocks -> 512B x8 blocks (2 consecutive waves per token).
//  - Pack (pos<<16)|tok into one u32 (tok < 2^16): one metadata load/token.

#define DIMS    1024
#define TOKENS  50257
#define WBITS   7
#define WSIZE   128
#define NW      ((TOKENS + WSIZE - 1) / WSIZE)   // 393 windows
#define PAD     129
#define NMAX    16384

// ---- fused counting sort: hist + scan + scatter, one workgroup ----
__global__ __launch_bounds__(1024) void sort_kernel(
    const int* __restrict__ x, int n,
    int* __restrict__ offs,                 // [NW+1]
    unsigned int* __restrict__ sorted)      // [n] packed (pos<<16)|tok
{
    __shared__ int xl[NMAX];                // 64 KB staged ids
    __shared__ int bins[NW];
    __shared__ int scanbuf[512];
    __shared__ int cursor[NW];
    const int t = threadIdx.x;

    // stage x into LDS (read HBM once), zero bins
    const bool fits = (n <= NMAX);
    if (fits) for (int i = t; i < n; i += 1024) xl[i] = x[i];
    if (t < NW) bins[t] = 0;
    __syncthreads();
    const int* xs = fits ? xl : x;

    // histogram (LDS atomics, ~42 hits/bin avg)
    for (int i = t; i < n; i += 1024)
        atomicAdd(&bins[xs[i] >> WBITS], 1);
    __syncthreads();

    // Hillis-Steele inclusive scan over 512 slots (NW=393 <= 512)
    if (t < 512) scanbuf[t] = (t < NW) ? bins[t] : 0;
    __syncthreads();
    for (int off = 1; off < 512; off <<= 1) {
        int u = 0;
        if (t < 512 && t >= off) u = scanbuf[t - off];
        __syncthreads();
        if (t < 512) scanbuf[t] += u;
        __syncthreads();
    }
    if (t < NW) {
        offs[t + 1] = scanbuf[t];           // inclusive prefix -> offs
        cursor[t]   = scanbuf[t] - bins[t]; // exclusive prefix -> write heads
    }
    if (t == 0) offs[0] = 0;
    __syncthreads();

    // scatter: stable order not required, any order within a window works
    for (int i = t; i < n; i += 1024) {
        int tok = xs[i];
        int p = atomicAdd(&cursor[tok >> WBITS], 1);
        sorted[p] = ((unsigned int)i << 16) | (unsigned int)tok;
    }
}

// Block (w, dchunk): stage W[dbase:dbase+128, w*128:(w+1)*128] into LDS
// (coalesced 512B/row reads), then each pair of waves writes one token's
// 128 dims contiguously (2 x 256B consecutive stores).
__global__ __launch_bounds__(512) void embed_main(
    const float* __restrict__ W,
    const int* __restrict__ offs,
    const unsigned int* __restrict__ sorted,
    float* __restrict__ out)
{
    __shared__ float tile[WSIZE * PAD];      // [dim_row][id_col], pad 129: (d+c)&31 banks
    const int w     = blockIdx.x;
    const int dbase = blockIdx.y * WSIZE;
    const int t     = threadIdx.x;
    const int id0   = w << WBITS;

    // issue the (uniform) window descriptor loads early
    const int beg = offs[w];
    const int nn  = offs[w + 1] - beg;

    const int c  = t & 127;                  // id column within window
    const int r0 = t >> 7;                   // 0..3
    const int id = id0 + c;
    if (id < TOKENS) {                       // last window partial (81 valid)
        #pragma unroll
        for (int i = 0; i < 32; ++i) {
            int r = (i << 2) + r0;           // dim row 0..127
            tile[r * PAD + c] = W[(size_t)(dbase + r) * TOKENS + id];
        }
    }
    __syncthreads();

    const int d  = t & 127;                  // lanes sweep 128 dims; wave = 256B contig
    const int jo = t >> 7;                   // 4 tokens in flight
    for (int jb = 0; jb < nn; jb += 4) {
        int j = jb + jo;
        if (j < nn) {
            unsigned int v = sorted[beg + j];
            int p   = (int)(v >> 16);
            int col = (int)(v & 0xFFFFu) - id0;
            out[(size_t)p * DIMS + dbase + d] = tile[d * PAD + col];
        }
    }
}

extern "C" void kernel_launch(void* const* d_in, const int* in_sizes, int n_in,
                              void* d_out, int out_size, void* d_ws, size_t ws_size,
                              hipStream_t stream) {
    const int*   x = (const int*)d_in[0];     // [16384]
    const float* W = (const float*)d_in[1];   // [1024, 50257]
    float*     out = (float*)d_out;

    const int n = in_sizes[0];                // 16384

    // workspace layout
    int* offs              = (int*)d_ws;              // NW+1
    unsigned int* sorted   = (unsigned int*)(offs + (NW + 1)); // n

    sort_kernel<<<1, 1024, 0, stream>>>(x, n, offs, sorted);

    dim3 grid(NW, DIMS / WSIZE);              // 393 x 8
    embed_main<<<grid, 512, 0, stream>>>(W, offs, sorted, out);
}